// Round 8
// baseline (174.717 us; speedup 1.0000x reference)
//
#include <hip/hip_runtime.h>
#include <math.h>

#define NN 50000
#define EE 800000
#define INDIM 256
#define DD 32
#define HH 8
#define CC 256   // H*D
#define NEG 0.01f
#define CAP 64   // bucket capacity per node; max degree ~40 for this graph (12-sigma margin)

typedef __attribute__((ext_vector_type(8))) short bf16x8;
typedef __attribute__((ext_vector_type(4))) float f32x4;

__device__ __forceinline__ unsigned short f32_to_bf16_rne(float f) {
  unsigned u = __float_as_uint(f);
  u += 0x7fffu + ((u >> 16) & 1u);
  return (unsigned short)(u >> 16);
}
__device__ __forceinline__ float bf16_to_f32(unsigned short b) {
  return __uint_as_float((unsigned)b << 16);
}

// ---------- fused: dtype-detect + convert + histogram + DIRECT bucket scatter + W->bf16 ----------
// Bucket layout: node n owns csr[n*CAP .. n*CAP+counts[n]); slot = histogram
// atomic return value. No scan, no compaction, no second pass.
__global__ __launch_bounds__(256) void k_prep(const unsigned* __restrict__ sraw,
                                              const unsigned* __restrict__ draw,
                                              int* __restrict__ counts,
                                              int* __restrict__ csr_src,
                                              const float* __restrict__ W,
                                              unsigned short* __restrict__ WbT) {
  __shared__ int sflag;
  if (threadIdx.x == 0) sflag = 0;
  __syncthreads();
  const int gt = blockIdx.x * 256 + threadIdx.x;
  unsigned v = 0;
#pragma unroll
  for (int i = 0; i < 4; ++i) {
    int e = (gt * 4 + i) % (EE / 2);
    v |= sraw[2 * e + 1] | draw[2 * e + 1];
  }
  if (v) atomicOr(&sflag, 1);
  __syncthreads();
  const int is32 = sflag;   // 1 => int32 indices

  const int stride = gridDim.x * blockDim.x;
  for (int e = gt; e < EE; e += stride) {
    int sv, dv;
    if (is32) {
      sv = ((const int*)sraw)[e];
      dv = ((const int*)draw)[e];
    } else {
      sv = (int)((const long long*)sraw)[e];
      dv = (int)((const long long*)draw)[e];
    }
    int slot = atomicAdd(&counts[dv], 1);
    csr_src[(dv << 6) + slot] = sv;
  }

  // W -> WbT[n][k] = W[h][k][d], n=h*32+d (B^T layout)
  if (gt < INDIM * CC) {
    int n = gt >> 8, k = gt & 255;
    int hh = n >> 5, d = n & 31;
    WbT[gt] = f32_to_bf16_rne(W[(size_t)hh * 8192 + k * 32 + d]);
  }
}

// ---------- z = h @ W via bf16 MFMA (swapped operands); el/er fused ----------
__global__ __launch_bounds__(512) void k_gemm(const float* __restrict__ h,
                                              const unsigned short* __restrict__ WbT,
                                              const float* __restrict__ attn_w,
                                              unsigned short* __restrict__ z,
                                              float* __restrict__ el,
                                              float* __restrict__ er) {
  __shared__ short sA[64 * 256];   // 32 KB, [64 nodes][256 k], chunk-swizzled
  const int t = threadIdx.x;
  const int l = t & 63;
  const int w = t >> 6;            // wave index == head
  const int row0 = blockIdx.x * 64;

#pragma unroll
  for (int i = 0; i < 4; ++i) {
    int q = i * 512 + t;
    int row = q >> 5, c = q & 31;
    int grow = row0 + row; if (grow >= NN) grow = NN - 1;
    const float* src = &h[(size_t)grow * 256 + c * 8];
    float4 f0 = *reinterpret_cast<const float4*>(src);
    float4 f1 = *reinterpret_cast<const float4*>(src + 4);
    bf16x8 vv;
    vv[0] = (short)f32_to_bf16_rne(f0.x); vv[1] = (short)f32_to_bf16_rne(f0.y);
    vv[2] = (short)f32_to_bf16_rne(f0.z); vv[3] = (short)f32_to_bf16_rne(f0.w);
    vv[4] = (short)f32_to_bf16_rne(f1.x); vv[5] = (short)f32_to_bf16_rne(f1.y);
    vv[6] = (short)f32_to_bf16_rne(f1.z); vv[7] = (short)f32_to_bf16_rne(f1.w);
    int sc = c ^ (row & 7);
    *reinterpret_cast<bf16x8*>(&sA[row * 256 + sc * 8]) = vv;
  }

  bf16x8 bf[2][8];
  {
    const int n = w * 32 + (l & 15);
    const int kb = (l >> 4) * 8;
#pragma unroll
    for (int c = 0; c < 2; ++c)
#pragma unroll
      for (int kk = 0; kk < 8; ++kk)
        bf[c][kk] = *reinterpret_cast<const bf16x8*>(
            &WbT[(size_t)(n + c * 16) * 256 + kk * 32 + kb]);
  }

  f32x4 acc[4][2];
#pragma unroll
  for (int m = 0; m < 4; ++m)
#pragma unroll
    for (int c = 0; c < 2; ++c) acc[m][c] = (f32x4){0.f, 0.f, 0.f, 0.f};

  __syncthreads();

#pragma unroll
  for (int kk = 0; kk < 8; ++kk) {
    bf16x8 af[4];
#pragma unroll
    for (int m = 0; m < 4; ++m) {
      int row = m * 16 + (l & 15);
      int chunk = kk * 4 + (l >> 4);
      int sc = chunk ^ (row & 7);
      af[m] = *reinterpret_cast<const bf16x8*>(&sA[row * 256 + sc * 8]);
    }
#pragma unroll
    for (int m = 0; m < 4; ++m)
#pragma unroll
      for (int c = 0; c < 2; ++c)
        acc[m][c] = __builtin_amdgcn_mfma_f32_16x16x32_bf16(bf[c][kk], af[m], acc[m][c], 0, 0, 0);
  }

  // acc[m][c][r]: node = row0+m*16+(l&15), feat = w*32 + c*16 + (l>>4)*4 + r
#pragma unroll
  for (int m = 0; m < 4; ++m) {
    int node = row0 + m * 16 + (l & 15);
    if (node < NN) {
#pragma unroll
      for (int c = 0; c < 2; ++c) {
        ushort4 pk;
        pk.x = f32_to_bf16_rne(acc[m][c][0]);
        pk.y = f32_to_bf16_rne(acc[m][c][1]);
        pk.z = f32_to_bf16_rne(acc[m][c][2]);
        pk.w = f32_to_bf16_rne(acc[m][c][3]);
        *reinterpret_cast<ushort4*>(
            &z[(size_t)node * CC + w * 32 + c * 16 + ((l >> 4) << 2)]) = pk;
      }
    }
  }

  float alc[2][4], arc[2][4];
#pragma unroll
  for (int c = 0; c < 2; ++c)
#pragma unroll
    for (int r = 0; r < 4; ++r) {
      int d = c * 16 + ((l >> 4) << 2) + r;
      alc[c][r] = attn_w[w * 64 + d];
      arc[c][r] = attn_w[w * 64 + 32 + d];
    }
#pragma unroll
  for (int m = 0; m < 4; ++m) {
    float pl = 0.f, pr = 0.f;
#pragma unroll
    for (int c = 0; c < 2; ++c)
#pragma unroll
      for (int r = 0; r < 4; ++r) {
        pl += acc[m][c][r] * alc[c][r];
        pr += acc[m][c][r] * arc[c][r];
      }
    pl += __shfl_xor(pl, 16); pl += __shfl_xor(pl, 32);
    pr += __shfl_xor(pr, 16); pr += __shfl_xor(pr, 32);
    if ((l >> 4) == 0) {
      int node = row0 + m * 16 + l;
      if (node < NN) {
        el[(size_t)node * HH + w] = pl;
        er[(size_t)node * HH + w] = pr;
      }
    }
  }
}

// ---------- per-node softmax-aggregate (round-4 form; bucket CSR) ----------
#define AGG_WAVES 8192
__global__ __launch_bounds__(256) void k_agg(const unsigned short* __restrict__ z,
                                             const float* __restrict__ el,
                                             const float* __restrict__ er,
                                             const int* __restrict__ counts,
                                             const int* __restrict__ csr_src,
                                             float* __restrict__ out) {
  const int gw = blockIdx.x * 4 + (threadIdx.x >> 6);
  const int l = threadIdx.x & 63;
  const int head = l >> 3;

  for (int n = gw; n < NN; n += AGG_WAVES) {
    const int beg = n << 6;                 // bucket base
    const int end = beg + counts[n];
    const float ern = er[(size_t)n * HH + head];

    float den = 0.f;
    float a0 = 0.f, a1 = 0.f, a2 = 0.f, a3 = 0.f;
#pragma unroll 4
    for (int p = beg; p < end; ++p) {
      int s = csr_src[p];
      float v = el[(size_t)s * HH + head] + ern;
      v = (v > 0.f) ? v : v * NEG;
      float wgt = __expf(v);
      ushort4 zv = *reinterpret_cast<const ushort4*>(&z[(size_t)s * CC + 4 * l]);
      den += wgt;
      a0 += wgt * bf16_to_f32(zv.x);
      a1 += wgt * bf16_to_f32(zv.y);
      a2 += wgt * bf16_to_f32(zv.z);
      a3 += wgt * bf16_to_f32(zv.w);
    }
    const float rd = (end > beg) ? (1.f / den) : 0.f;
    float4 o;
    o.x = a0 * rd; o.y = a1 * rd; o.z = a2 * rd; o.w = a3 * rd;
    *reinterpret_cast<float4*>(&out[(size_t)n * CC + 4 * l]) = o;
  }
}

extern "C" void kernel_launch(void* const* d_in, const int* in_sizes, int n_in,
                              void* d_out, int out_size, void* d_ws, size_t ws_size,
                              hipStream_t stream) {
  const float* h      = (const float*)d_in[0];
  const float* W      = (const float*)d_in[1];
  const float* attn_w = (const float*)d_in[2];
  const void*  src_raw = d_in[3];
  const void*  dst_raw = d_in[4];
  float* out = (float*)d_out;

  char* ws = (char*)d_ws;
  size_t off = 0;
  unsigned short* z   = (unsigned short*)(ws + off); off += (size_t)NN * CC * 2;     // 25.6 MB
  unsigned short* WbT = (unsigned short*)(ws + off); off += (size_t)INDIM * CC * 2;  // 128 KB
  float* el = (float*)(ws + off); off += (size_t)NN * HH * 4;   // 1.6 MB
  float* er = (float*)(ws + off); off += (size_t)NN * HH * 4;   // 1.6 MB
  int* counts  = (int*)(ws + off); off += (size_t)NN * 4;       // 200 KB (memset)
  int* csr_src = (int*)(ws + off); off += (size_t)NN * CAP * 4; // 12.8 MB

  hipMemsetAsync(counts, 0, (size_t)NN * 4, stream);

  k_prep<<<1024, 256, 0, stream>>>((const unsigned*)src_raw, (const unsigned*)dst_raw,
                                   counts, csr_src, W, WbT);

  k_gemm<<<(NN + 63) / 64, 512, 0, stream>>>(h, WbT, attn_w, z, el, er);

  k_agg<<<AGG_WAVES / 4, 256, 0, stream>>>(z, el, er, counts, csr_src, out);
}